// Round 10
// baseline (459.602 us; speedup 1.0000x reference)
//
#include <hip/hip_runtime.h>
#include <hip/hip_bf16.h>

// MACE layer forward, MI355X (gfx950). f32 I/O, bf16 internals.
// Round 10: (1) k_pre/k_post stage node rows in LDS (coalesced float4) and
// pack MFMA A-frags from LDS -- kills ~96 scalar global loads per lane for
// the stride-3 v components. (2) k_edge: 512-thr blocks, ONE tile-group per
// wave (Bf 80->40 VGPRs) + on-the-fly dot/cross at p=3/4 (-16 regs) so the
// natural allocation fits under the 128 cliff without a forced cap (R9 cap
// caused 37MB spill WRITE). hid compute spread over 512 threads.

#define NN 10000
#define EE 320000
#define FEPS 0.17677669529663687f

typedef __attribute__((ext_vector_type(4))) float f32x4;
typedef __attribute__((ext_vector_type(8))) short s16x8;

__device__ __forceinline__ float bflo(unsigned u) { return __uint_as_float(u << 16); }
__device__ __forceinline__ float bfhi(unsigned u) { return __uint_as_float(u & 0xffff0000u); }
__device__ __forceinline__ unsigned short f2bu(float f) {
    unsigned u = __float_as_uint(f);
    return (unsigned short)((u + 0x7FFFu + ((u >> 16) & 1u)) >> 16);
}
__device__ __forceinline__ unsigned pack2(float a, float b) {
    return (unsigned)f2bu(a) | ((unsigned)f2bu(b) << 16);
}
__device__ __forceinline__ s16x8 pack8(float4 a, float4 b) {
    union { s16x8 v; unsigned short u[8]; } r;
    r.u[0] = f2bu(a.x); r.u[1] = f2bu(a.y); r.u[2] = f2bu(a.z); r.u[3] = f2bu(a.w);
    r.u[4] = f2bu(b.x); r.u[5] = f2bu(b.y); r.u[6] = f2bu(b.z); r.u[7] = f2bu(b.w);
    return r.v;
}

// ---------------- CSR build ----------------
__global__ void k_hist(const int* __restrict__ recv, int* __restrict__ cnt) {
    int e = blockIdx.x * blockDim.x + threadIdx.x;
    if (e < EE) {
        int r = recv[e];
        r = ((unsigned)r < NN) ? r : 0;
        atomicAdd(&cnt[r], 1);
    }
}

__global__ void k_fill(const int* __restrict__ recv, int* __restrict__ cur,
                       int* __restrict__ csr) {
    int e = blockIdx.x * blockDim.x + threadIdx.x;
    if (e < EE) {
        int r = recv[e];
        r = ((unsigned)r < NN) ? r : 0;
        int slot = atomicAdd(&cur[r], 1);
        if ((unsigned)slot < EE) csr[slot] = e;
    }
}

// ---- prep: weight tables (26 mats transposed bf16) + w2t + cnt zero ----
#define TWN (26 * 16384)
#define W2N (640 * 64)
__global__ void k_prep(const float* __restrict__ Wus, const float* __restrict__ Wuv,
                       const float* __restrict__ Wds, const float* __restrict__ Wdv,
                       const float* __restrict__ Wls, const float* __restrict__ Wlv,
                       const float* __restrict__ Wss, const float* __restrict__ Wsv,
                       const float* __restrict__ W_rad2,
                       unsigned short* __restrict__ T,
                       unsigned short* __restrict__ w2t,
                       int* __restrict__ cnt) {
    int idx = blockIdx.x * 256 + threadIdx.x;
    if (idx < TWN) {
        const int m = idx >> 14, p = idx & 16383, d = p >> 7, c = p & 127;
        const float* src;
        if (m == 0) src = Wus; else if (m == 1) src = Wuv;
        else if (m == 2) src = Wds; else if (m == 3) src = Wdv;
        else if (m == 4) src = Wls; else if (m == 5) src = Wlv;
        else if (m < 16) src = Wss + (size_t)(m - 6) * 16384;
        else src = Wsv + (size_t)(m - 16) * 16384;
        T[(size_t)m * 16384 + d * 128 + c] = f2bu(src[c * 128 + d]);
    } else if (idx < TWN + W2N) {
        const int i = idx - TWN;
        const int n = i >> 6, k = i & 63;
        w2t[i] = f2bu(W_rad2[k * 640 + n]);
    } else if (idx < TWN + W2N + NN) {
        cnt[idx - TWN - W2N] = 0;
    }
}

// ---- scan (CSR offsets) + species buckets, one 1024-thread block ----
__global__ __launch_bounds__(1024) void k_scan_spec(
    const int* __restrict__ cnt, int* __restrict__ offs, int* __restrict__ cur,
    const int* __restrict__ specie, int* __restrict__ perm,
    int2* __restrict__ tiles, int* __restrict__ ntiles) {
    __shared__ int sums[1024];
    __shared__ int hcnt[10], hbase[10], hcur[10], tbase[11];
    const int t = threadIdx.x;
    const int chunk = (NN + 1023) / 1024;  // 10
    const int start = t * chunk;
    int local = 0;
    for (int i = 0; i < chunk; i++) {
        int idx = start + i;
        if (idx < NN) local += cnt[idx];
    }
    sums[t] = local;
    __syncthreads();
    for (int ofs = 1; ofs < 1024; ofs <<= 1) {
        int u = (t >= ofs) ? sums[t - ofs] : 0;
        __syncthreads();
        sums[t] += u;
        __syncthreads();
    }
    int base = (t == 0) ? 0 : sums[t - 1];
    for (int i = 0; i < chunk; i++) {
        int idx = start + i;
        if (idx < NN) {
            offs[idx] = base;
            cur[idx] = base;
            base += cnt[idx];
        }
    }
    if (t == 0) offs[NN] = sums[1023];
    if (t < 10) hcnt[t] = 0;
    __syncthreads();
    for (int n = t; n < NN; n += 1024) {
        int s = specie[n];
        s = ((unsigned)s < 10) ? s : 0;
        atomicAdd(&hcnt[s], 1);
    }
    __syncthreads();
    if (t == 0) {
        int run = 0, tc = 0;
        for (int sp = 0; sp < 10; sp++) {
            hbase[sp] = run; hcur[sp] = run; run += hcnt[sp];
            tbase[sp] = tc;  tc += (hcnt[sp] + 15) >> 4;
        }
        tbase[10] = tc;
        *ntiles = tc;
    }
    __syncthreads();
    const int tc = tbase[10];
    for (int ti = t; ti < tc; ti += 1024) {
        int sp = 0;
        while (sp < 9 && ti >= tbase[sp + 1]) sp++;
        const int b = (ti - tbase[sp]) * 16;
        tiles[ti] = make_int2(hbase[sp] + b, (sp << 8) | min(16, hcnt[sp] - b));
    }
    for (int n = t; n < NN; n += 1024) {
        int s = specie[n];
        s = ((unsigned)s < 10) ? s : 0;
        int slot = atomicAdd(&hcur[s], 1);
        if ((unsigned)slot < NN) perm[slot] = n;
    }
}

// ---------------- pre: h = [s,v]@W_up via MFMA -> h4 interleaved ----------
__global__ __launch_bounds__(256) void k_pre_mfma(
    const float* __restrict__ nf,
    const unsigned short* __restrict__ Tw,
    uint2* __restrict__ h4) {
    const int tile = blockIdx.x;  // 625 tiles of 16 nodes
    const int tid = threadIdx.x;
    const int lane = tid & 63, wv = tid >> 6;
    const int col = lane & 15, quad = lane >> 4;
    __shared__ float nfl[16][512];  // 32 KB
    {
        const float4* src = (const float4*)(nf + (size_t)tile * 16 * 512);
        float4* dst = (float4*)nfl;
        for (int i = tid; i < 2048; i += 256) dst[i] = src[i];
    }
    __syncthreads();
    const float* rp = nfl[col];
    s16x8 Af[4][4];
#pragma unroll
    for (int kt = 0; kt < 4; kt++) {
        const int ko = kt * 32 + quad * 8;
        const float4 fa = *(const float4*)(rp + ko);
        const float4 fb = *(const float4*)(rp + ko + 4);
        Af[0][kt] = pack8(fa, fb);
#pragma unroll
        for (int i = 0; i < 3; i++) {
            union { s16x8 v; unsigned short u[8]; } A;
#pragma unroll
            for (int j = 0; j < 8; j++) A.u[j] = f2bu(rp[128 + 3 * (ko + j) + i]);
            Af[1 + i][kt] = A.v;
        }
    }
    const unsigned short* Ts = Tw;
    const unsigned short* Tv = Tw + 16384;
#pragma unroll
    for (int nt = 0; nt < 2; nt++) {
        const int d = 32 * wv + 16 * nt + col;
        f32x4 C[4];
#pragma unroll
        for (int m = 0; m < 4; m++) C[m] = (f32x4){0.f, 0.f, 0.f, 0.f};
#pragma unroll
        for (int kt = 0; kt < 4; kt++) {
            const int ko = kt * 32 + quad * 8;
            const s16x8 Bs = *(const s16x8*)&Ts[(size_t)d * 128 + ko];
            const s16x8 Bv = *(const s16x8*)&Tv[(size_t)d * 128 + ko];
            C[0] = __builtin_amdgcn_mfma_f32_16x16x32_bf16(Af[0][kt], Bs, C[0], 0, 0, 0);
#pragma unroll
            for (int i = 0; i < 3; i++)
                C[1 + i] = __builtin_amdgcn_mfma_f32_16x16x32_bf16(Af[1 + i][kt], Bv, C[1 + i], 0, 0, 0);
        }
#pragma unroll
        for (int reg = 0; reg < 4; reg++) {
            const int node = tile * 16 + quad * 4 + reg;
            h4[(size_t)node * 128 + d] =
                make_uint2(pack2(C[0][reg], C[1][reg]), pack2(C[2][reg], C[3][reg]));
        }
    }
}

// ------- MFMA edge kernel: 512 thr, 1 tile-group per wave ------
#define EGRID 2560
__global__ __launch_bounds__(512) void k_edge_mfma(
    const float* __restrict__ vectors,
    const float* __restrict__ radial,
    const int* __restrict__ senders,
    const float* __restrict__ W_rad1,
    const unsigned short* __restrict__ w2t,   // [640][64] bf16
    const uint2* __restrict__ h4,             // [N][128] {s,v0,v1,v2} bf16
    const int* __restrict__ offs, const int* __restrict__ csr,
    unsigned short* __restrict__ aggb) {      // [N][4][128] bf16 planar
    __shared__ unsigned short w1s[512];
    __shared__ float4 em[64];
    __shared__ float radl[64][8];
    __shared__ unsigned short hid[64 * 72];
    const int tid = threadIdx.x;
    const int lane = tid & 63, wv = tid >> 6;   // wv in [0,8) = tile-group
    const int row = lane & 15, quad = lane >> 4;
    if (tid < 512) w1s[tid] = f2bu(W_rad1[tid]);

    // B-frags for this wave's tile-group: 10 frags = 40 VGPRs
    s16x8 Bf[5][2];
#pragma unroll
    for (int p = 0; p < 5; p++) {
        const unsigned short* bp =
            w2t + (size_t)(128 * p + 16 * wv + row) * 64 + quad * 8;
        Bf[p][0] = *(const s16x8*)(bp);
        Bf[p][1] = *(const s16x8*)(bp + 32);
    }
    const int c = 16 * wv + row;  // this lane's channel

    for (int n = blockIdx.x; n < NN; n += EGRID) {
        const int start = offs[n];
        const int deg = offs[n + 1] - start;
        float acc_s = 0.f, av0 = 0.f, av1 = 0.f, av2 = 0.f;

        for (int c0 = 0; c0 < deg; c0 += 64) {
            __syncthreads();
            if (tid < 64) {
                const int i = tid, gi = c0 + i;
                if (gi < deg) {
                    int e = csr[start + gi];
                    e = ((unsigned)e < EE) ? e : 0;
                    int j = senders[e];
                    j = ((unsigned)j < NN) ? j : 0;
                    const float vx = vectors[e * 3 + 0];
                    const float vy = vectors[e * 3 + 1];
                    const float vz = vectors[e * 3 + 2];
                    const float inr = 1.7320508075688772f /
                        (sqrtf(vx * vx + vy * vy + vz * vz) + 1e-9f);
                    em[i] = make_float4(__int_as_float(j), vx * inr, vy * inr, vz * inr);
                    *(float4*)&radl[i][0] = *(const float4*)(radial + (size_t)e * 8);
                    *(float4*)&radl[i][4] = *(const float4*)(radial + (size_t)e * 8 + 4);
                } else {
                    em[i] = make_float4(0.f, 0.f, 0.f, 0.f);
                    *(float4*)&radl[i][0] = make_float4(0.f, 0.f, 0.f, 0.f);
                    *(float4*)&radl[i][4] = make_float4(0.f, 0.f, 0.f, 0.f);
                }
            }
            __syncthreads();
            {   // cooperative hid: thread computes 8 units of one edge
                const int eL = tid >> 3, u0 = (tid & 7) * 8;
                float a[8];
#pragma unroll
                for (int u = 0; u < 8; u++) a[u] = 0.f;
#pragma unroll
                for (int r = 0; r < 8; r++) {
                    const uint4 wa = *(const uint4*)&w1s[r * 64 + u0];
                    const float f = radl[eL][r];
                    a[0] += f * bflo(wa.x); a[1] += f * bfhi(wa.x);
                    a[2] += f * bflo(wa.y); a[3] += f * bfhi(wa.y);
                    a[4] += f * bflo(wa.z); a[5] += f * bfhi(wa.z);
                    a[6] += f * bflo(wa.w); a[7] += f * bfhi(wa.w);
                }
                unsigned o[4];
#pragma unroll
                for (int k = 0; k < 4; k++) {
                    const float s0 = a[2 * k] / (1.f + __expf(-a[2 * k]));
                    const float s1 = a[2 * k + 1] / (1.f + __expf(-a[2 * k + 1]));
                    o[k] = pack2(s0, s1);
                }
                *(uint4*)&hid[eL * 72 + u0] = make_uint4(o[0], o[1], o[2], o[3]);
            }
            __syncthreads();
            const int glim = min(64, deg - c0);
            for (int g0 = 0; g0 < glim; g0 += 16) {
                const s16x8 A0 = *(const s16x8*)&hid[(g0 + row) * 72 + quad * 8];
                const s16x8 A1 = *(const s16x8*)&hid[(g0 + row) * 72 + 32 + quad * 8];
                int jr[4]; float yr0[4], yr1[4], yr2[4];
#pragma unroll
                for (int rg = 0; rg < 4; rg++) {
                    const float4 m = em[g0 + quad * 4 + rg];
                    jr[rg] = __float_as_int(m.x);
                    yr0[rg] = m.y; yr1[rg] = m.z; yr2[rg] = m.w;
                }
                float sj[4], a0r[4], a1r[4], a2r[4];
#pragma unroll
                for (int rg = 0; rg < 4; rg++) {
                    const uint2 hh = h4[(size_t)jr[rg] * 128 + c];
                    sj[rg] = bflo(hh.x); a0r[rg] = bfhi(hh.x);
                    a1r[rg] = bflo(hh.y); a2r[rg] = bfhi(hh.y);
                }
#pragma unroll
                for (int p = 0; p < 5; p++) {
                    f32x4 z = {0.f, 0.f, 0.f, 0.f};
                    z = __builtin_amdgcn_mfma_f32_16x16x32_bf16(A0, Bf[p][0], z, 0, 0, 0);
                    z = __builtin_amdgcn_mfma_f32_16x16x32_bf16(A1, Bf[p][1], z, 0, 0, 0);
#pragma unroll
                    for (int rg = 0; rg < 4; rg++) {
                        const float w = z[rg];
                        if (p == 0) {
                            acc_s += w * sj[rg];
                        } else if (p == 1) {
                            const float ws = w * sj[rg];
                            av0 += ws * yr0[rg];
                            av1 += ws * yr1[rg];
                            av2 += ws * yr2[rg];
                        } else if (p == 2) {
                            av0 += w * a0r[rg];
                            av1 += w * a1r[rg];
                            av2 += w * a2r[rg];
                        } else if (p == 3) {
                            acc_s += w * (a0r[rg] * yr0[rg] + a1r[rg] * yr1[rg] +
                                          a2r[rg] * yr2[rg]);
                        } else {
                            av0 += w * (a1r[rg] * yr2[rg] - a2r[rg] * yr1[rg]);
                            av1 += w * (a2r[rg] * yr0[rg] - a0r[rg] * yr2[rg]);
                            av2 += w * (a0r[rg] * yr1[rg] - a1r[rg] * yr0[rg]);
                        }
                    }
                }
            }
        }
        acc_s += __shfl_xor(acc_s, 16); acc_s += __shfl_xor(acc_s, 32);
        av0 += __shfl_xor(av0, 16);     av0 += __shfl_xor(av0, 32);
        av1 += __shfl_xor(av1, 16);     av1 += __shfl_xor(av1, 32);
        av2 += __shfl_xor(av2, 16);     av2 += __shfl_xor(av2, 32);
        if (lane < 16) {
            unsigned short* og = aggb + (size_t)n * 512;
            const int cc = 16 * wv + lane;
            og[cc] = f2bu(acc_s);
            og[128 + cc] = f2bu(av0);
            og[256 + cc] = f2bu(av1);
            og[384 + cc] = f2bu(av2);
        }
    }
}

// -------- post: down+skip GEMM -> prod -> P via LDS -> lin GEMM + out ------
__global__ __launch_bounds__(256) void k_post_mfma(
    const float* __restrict__ nf,
    const unsigned short* __restrict__ aggb,
    const int* __restrict__ perm,
    const int2* __restrict__ tiles,
    const int* __restrict__ ntiles,
    const unsigned short* __restrict__ Tw,
    const float* __restrict__ Wps,
    const float* __restrict__ Wpv,
    const float* __restrict__ Wro,
    float* __restrict__ dout) {
    const int tile = blockIdx.x;
    if (tile >= *ntiles) return;
    const int2 td = tiles[tile];
    const int base = td.x, sp = td.y >> 8, cnt = td.y & 255;
    __shared__ int nodesl[16];
    __shared__ float rol[16];
    __shared__ unsigned short Pl[4][16][128];  // 16 KB
    __shared__ float nfl[16][512];             // 32 KB
    const int tid = threadIdx.x;
    if (tid < 16) {
        nodesl[tid] = perm[base + ((tid < cnt) ? tid : 0)];
        rol[tid] = 0.f;
    }
    __syncthreads();
    {   // stage the 16 (permuted) node rows, coalesced
        float4* dst = (float4*)nfl;
        for (int i = tid; i < 2048; i += 256) {
            const int r = i >> 7, off = i & 127;
            dst[i] = ((const float4*)(nf + (size_t)nodesl[r] * 512))[off];
        }
    }
    __syncthreads();
    const int lane = tid & 63, wv = tid >> 6;
    const int col = lane & 15, quad = lane >> 4;
    const int aN = nodesl[col];
    const unsigned short* Tds = Tw + (size_t)2 * 16384;
    const unsigned short* Tdv = Tw + (size_t)3 * 16384;
    const unsigned short* Tls = Tw + (size_t)4 * 16384;
    const unsigned short* Tlv = Tw + (size_t)5 * 16384;
    const unsigned short* Tss = Tw + (size_t)(6 + sp) * 16384;
    const unsigned short* Tsv = Tw + (size_t)(16 + sp) * 16384;
    const float* rp = nfl[col];
    f32x4 SC[2][4];
#pragma unroll
    for (int nt = 0; nt < 2; nt++) {
        const int d = 32 * wv + 16 * nt + col;
        f32x4 CF[4];
#pragma unroll
        for (int m = 0; m < 4; m++) CF[m] = (f32x4){0.f, 0.f, 0.f, 0.f};
#pragma unroll
        for (int kt = 0; kt < 4; kt++) {
            const int ko = kt * 32 + quad * 8;
            const s16x8 Bs = *(const s16x8*)&Tds[(size_t)d * 128 + ko];
            const s16x8 Bv = *(const s16x8*)&Tdv[(size_t)d * 128 + ko];
#pragma unroll
            for (int m = 0; m < 4; m++) {
                const s16x8 A = *(const s16x8*)&aggb[(size_t)aN * 512 + m * 128 + ko];
                CF[m] = __builtin_amdgcn_mfma_f32_16x16x32_bf16(A, m ? Bv : Bs, CF[m], 0, 0, 0);
            }
        }
        const float wps0 = Wps[sp * 384 + d];
        const float wps1 = Wps[sp * 384 + 128 + d];
        const float wps2 = Wps[sp * 384 + 256 + d];
        const float wpv0 = Wpv[sp * 256 + d];
        const float wpv1 = Wpv[sp * 256 + 128 + d];
#pragma unroll
        for (int reg = 0; reg < 4; reg++) {
            const float fs = CF[0][reg] * FEPS;
            const float f0 = CF[1][reg] * FEPS;
            const float f1 = CF[2][reg] * FEPS;
            const float f2 = CF[3][reg] * FEPS;
            const float ps = fs * wps0 + fs * fs * wps1 + (f0 * f0 + f1 * f1 + f2 * f2) * wps2;
            const float pb = wpv0 + fs * wpv1;
            const int r = quad * 4 + reg;
            Pl[0][r][d] = f2bu(ps);
            Pl[1][r][d] = f2bu(f0 * pb);
            Pl[2][r][d] = f2bu(f1 * pb);
            Pl[3][r][d] = f2bu(f2 * pb);
        }
        f32x4 CS[4];
#pragma unroll
        for (int m = 0; m < 4; m++) CS[m] = (f32x4){0.f, 0.f, 0.f, 0.f};
#pragma unroll
        for (int kt = 0; kt < 4; kt++) {
            const int ko = kt * 32 + quad * 8;
            const s16x8 Bss = *(const s16x8*)&Tss[(size_t)d * 128 + ko];
            const s16x8 Bsv = *(const s16x8*)&Tsv[(size_t)d * 128 + ko];
            const float4 fa = *(const float4*)(rp + ko);
            const float4 fb = *(const float4*)(rp + ko + 4);
            CS[0] = __builtin_amdgcn_mfma_f32_16x16x32_bf16(pack8(fa, fb), Bss, CS[0], 0, 0, 0);
#pragma unroll
            for (int i = 0; i < 3; i++) {
                union { s16x8 v; unsigned short u[8]; } A;
#pragma unroll
                for (int j = 0; j < 8; j++) A.u[j] = f2bu(rp[128 + 3 * (ko + j) + i]);
                CS[1 + i] = __builtin_amdgcn_mfma_f32_16x16x32_bf16(A.v, Bsv, CS[1 + i], 0, 0, 0);
            }
        }
#pragma unroll
        for (int m = 0; m < 4; m++) SC[nt][m] = CS[m];
    }
    __syncthreads();
#pragma unroll
    for (int nt = 0; nt < 2; nt++) {
        const int d = 32 * wv + 16 * nt + col;
        f32x4 CL[4];
#pragma unroll
        for (int m = 0; m < 4; m++) CL[m] = (f32x4){0.f, 0.f, 0.f, 0.f};
#pragma unroll
        for (int kt = 0; kt < 4; kt++) {
            const int ko = kt * 32 + quad * 8;
            const s16x8 Bls = *(const s16x8*)&Tls[(size_t)d * 128 + ko];
            const s16x8 Blv = *(const s16x8*)&Tlv[(size_t)d * 128 + ko];
#pragma unroll
            for (int m = 0; m < 4; m++) {
                const s16x8 A = *(const s16x8*)&Pl[m][col][ko];
                CL[m] = __builtin_amdgcn_mfma_f32_16x16x32_bf16(A, m ? Blv : Bls, CL[m], 0, 0, 0);
            }
        }
        const float wro = Wro[d];
#pragma unroll
        for (int reg = 0; reg < 4; reg++) {
            const int r = quad * 4 + reg;
            if (r < cnt) {
                const int node = nodesl[r];
                const float outs = CL[0][reg] + SC[nt][0][reg];
                const float o0 = CL[1][reg] + SC[nt][1][reg];
                const float o1 = CL[2][reg] + SC[nt][2][reg];
                const float o2 = CL[3][reg] + SC[nt][3][reg];
                float* o = dout + NN + (size_t)node * 512;
                o[d] = outs;
                o[128 + 3 * d + 0] = o0;
                o[128 + 3 * d + 1] = o1;
                o[128 + 3 * d + 2] = o2;
                atomicAdd(&rol[r], outs * wro);
            }
        }
    }
    __syncthreads();
    if (tid < 16 && tid < cnt) dout[nodesl[tid]] = rol[tid];
}

extern "C" void kernel_launch(void* const* d_in, const int* in_sizes, int n_in,
                              void* d_out, int out_size, void* d_ws, size_t ws_size,
                              hipStream_t stream) {
    const float* vectors    = (const float*)d_in[0];
    const float* node_feats = (const float*)d_in[1];
    const int*   specie     = (const int*)d_in[2];
    const float* radial     = (const float*)d_in[3];
    const int*   senders    = (const int*)d_in[4];
    const int*   receivers  = (const int*)d_in[5];
    const float* W_up_s     = (const float*)d_in[6];
    const float* W_up_v     = (const float*)d_in[7];
    const float* W_rad1     = (const float*)d_in[8];
    const float* W_rad2     = (const float*)d_in[9];
    const float* W_down_s   = (const float*)d_in[10];
    const float* W_down_v   = (const float*)d_in[11];
    const float* W_skip_s   = (const float*)d_in[12];
    const float* W_skip_v   = (const float*)d_in[13];
    const float* W_prod_s   = (const float*)d_in[14];
    const float* W_prod_v   = (const float*)d_in[15];
    const float* W_lin_s    = (const float*)d_in[16];
    const float* W_lin_v    = (const float*)d_in[17];
    const float* W_ro       = (const float*)d_in[18];
    float* out = (float*)d_out;

    // workspace carve (~23 MB)
    char* w = (char*)d_ws;
    auto align256 = [](size_t x) { return (x + 255) & ~(size_t)255; };
    int* cnt  = (int*)w;              w += align256((size_t)NN * 4);
    int* offs = (int*)w;              w += align256((size_t)(NN + 1) * 4);
    int* cur  = (int*)w;              w += align256((size_t)NN * 4);
    int* csr  = (int*)w;              w += align256((size_t)EE * 4);
    uint2* h4 = (uint2*)w;            w += align256((size_t)NN * 128 * 8);
    unsigned short* aggb = (unsigned short*)w;  w += align256((size_t)NN * 512 * 2);
    unsigned short* w2t  = (unsigned short*)w;  w += align256((size_t)W2N * 2);
    unsigned short* Tw   = (unsigned short*)w;  w += align256((size_t)TWN * 2);
    int* perm   = (int*)w;            w += align256((size_t)NN * 4);
    int2* tiles = (int2*)w;           w += align256((size_t)640 * 8);
    int* ntiles = (int*)w;            w += align256(4);

    k_prep<<<(TWN + W2N + NN + 255) / 256, 256, 0, stream>>>(
        W_up_s, W_up_v, W_down_s, W_down_v, W_lin_s, W_lin_v,
        W_skip_s, W_skip_v, W_rad2, Tw, w2t, cnt);
    k_hist<<<(EE + 255) / 256, 256, 0, stream>>>(receivers, cnt);
    k_scan_spec<<<1, 1024, 0, stream>>>(cnt, offs, cur, specie, perm, tiles, ntiles);
    k_fill<<<(EE + 255) / 256, 256, 0, stream>>>(receivers, cur, csr);
    k_pre_mfma<<<NN / 16, 256, 0, stream>>>(node_feats, Tw, h4);
    k_edge_mfma<<<EGRID, 512, 0, stream>>>(vectors, radial, senders, W_rad1,
                                           w2t, h4, offs, csr, aggb);
    k_post_mfma<<<640, 256, 0, stream>>>(node_feats, aggb, perm, tiles, ntiles,
                                         Tw, W_prod_s, W_prod_v, W_ro, out);
}

// Round 11
// 451.820 us; speedup vs baseline: 1.0172x; 1.0172x over previous
//
#include <hip/hip_runtime.h>
#include <hip/hip_bf16.h>

// MACE layer forward, MI355X (gfx950). f32 I/O, bf16 internals.
// Round 11: hybrid k_edge = R9 shape (256 thr, 4 waves, 2 tile-groups/wave;
// 512-thr R10 regressed: 8-wave barriers + 1/8 staging util) + R10 register
// diet (on-the-fly dot/cross, -16 regs) -> natural ~116 VGPR fits under the
// 128 cliff; (256,2) cap kept as non-binding safety (R9: cap==128).
// k_prep: LDS-tile transpose for the 26 weight mats (was 512B-stride
// uncoalesced reads). pre/post unchanged from R10 (LDS-staged, helped).

#define NN 10000
#define EE 320000
#define FEPS 0.17677669529663687f

typedef __attribute__((ext_vector_type(4))) float f32x4;
typedef __attribute__((ext_vector_type(8))) short s16x8;

__device__ __forceinline__ float bflo(unsigned u) { return __uint_as_float(u << 16); }
__device__ __forceinline__ float bfhi(unsigned u) { return __uint_as_float(u & 0xffff0000u); }
__device__ __forceinline__ unsigned short f2bu(float f) {
    unsigned u = __float_as_uint(f);
    return (unsigned short)((u + 0x7FFFu + ((u >> 16) & 1u)) >> 16);
}
__device__ __forceinline__ unsigned pack2(float a, float b) {
    return (unsigned)f2bu(a) | ((unsigned)f2bu(b) << 16);
}
__device__ __forceinline__ s16x8 pack8(float4 a, float4 b) {
    union { s16x8 v; unsigned short u[8]; } r;
    r.u[0] = f2bu(a.x); r.u[1] = f2bu(a.y); r.u[2] = f2bu(a.z); r.u[3] = f2bu(a.w);
    r.u[4] = f2bu(b.x); r.u[5] = f2bu(b.y); r.u[6] = f2bu(b.z); r.u[7] = f2bu(b.w);
    return r.v;
}

// ---------------- CSR build ----------------
__global__ void k_hist(const int* __restrict__ recv, int* __restrict__ cnt) {
    int e = blockIdx.x * blockDim.x + threadIdx.x;
    if (e < EE) {
        int r = recv[e];
        r = ((unsigned)r < NN) ? r : 0;
        atomicAdd(&cnt[r], 1);
    }
}

__global__ void k_fill(const int* __restrict__ recv, int* __restrict__ cur,
                       int* __restrict__ csr) {
    int e = blockIdx.x * blockDim.x + threadIdx.x;
    if (e < EE) {
        int r = recv[e];
        r = ((unsigned)r < NN) ? r : 0;
        int slot = atomicAdd(&cur[r], 1);
        if ((unsigned)slot < EE) csr[slot] = e;
    }
}

// ---- prep: blocks 0..25 transpose one 128x128 weight mat via LDS tile;
//      blocks 26.. handle w2t (strided but tiny) + cnt zeroing ----
#define TWN (26 * 16384)
#define W2N (640 * 64)
#define PREPX 20
__global__ __launch_bounds__(256) void k_prep(
    const float* __restrict__ Wus, const float* __restrict__ Wuv,
    const float* __restrict__ Wds, const float* __restrict__ Wdv,
    const float* __restrict__ Wls, const float* __restrict__ Wlv,
    const float* __restrict__ Wss, const float* __restrict__ Wsv,
    const float* __restrict__ W_rad2,
    unsigned short* __restrict__ T,
    unsigned short* __restrict__ w2t,
    int* __restrict__ cnt) {
    const int b = blockIdx.x, tid = threadIdx.x;
    if (b < 26) {
        __shared__ unsigned short tr[128][130];  // pad 130: 2-way free
        const int m = b;
        const float* src;
        if (m == 0) src = Wus; else if (m == 1) src = Wuv;
        else if (m == 2) src = Wds; else if (m == 3) src = Wdv;
        else if (m == 4) src = Wls; else if (m == 5) src = Wlv;
        else if (m < 16) src = Wss + (size_t)(m - 6) * 16384;
        else src = Wsv + (size_t)(m - 16) * 16384;
        for (int i = tid; i < 16384; i += 256) {
            const int c = i >> 7, d = i & 127;   // coalesced read of src[c][d]
            tr[d][c] = f2bu(src[i]);
        }
        __syncthreads();
        unsigned* o32 = (unsigned*)(T + (size_t)m * 16384);
        for (int i = tid; i < 8192; i += 256) {  // coalesced u32 write
            const int d = i >> 6, c2 = (i & 63) * 2;
            o32[i] = (unsigned)tr[d][c2] | ((unsigned)tr[d][c2 + 1] << 16);
        }
    } else {
        for (int i = (b - 26) * 256 + tid; i < W2N + NN; i += PREPX * 256) {
            if (i < W2N) {
                const int n = i >> 6, k = i & 63;
                w2t[i] = f2bu(W_rad2[k * 640 + n]);
            } else {
                cnt[i - W2N] = 0;
            }
        }
    }
}

// ---- scan (CSR offsets) + species buckets, one 1024-thread block ----
__global__ __launch_bounds__(1024) void k_scan_spec(
    const int* __restrict__ cnt, int* __restrict__ offs, int* __restrict__ cur,
    const int* __restrict__ specie, int* __restrict__ perm,
    int2* __restrict__ tiles, int* __restrict__ ntiles) {
    __shared__ int sums[1024];
    __shared__ int hcnt[10], hbase[10], hcur[10], tbase[11];
    const int t = threadIdx.x;
    const int chunk = (NN + 1023) / 1024;  // 10
    const int start = t * chunk;
    int local = 0;
    for (int i = 0; i < chunk; i++) {
        int idx = start + i;
        if (idx < NN) local += cnt[idx];
    }
    sums[t] = local;
    __syncthreads();
    for (int ofs = 1; ofs < 1024; ofs <<= 1) {
        int u = (t >= ofs) ? sums[t - ofs] : 0;
        __syncthreads();
        sums[t] += u;
        __syncthreads();
    }
    int base = (t == 0) ? 0 : sums[t - 1];
    for (int i = 0; i < chunk; i++) {
        int idx = start + i;
        if (idx < NN) {
            offs[idx] = base;
            cur[idx] = base;
            base += cnt[idx];
        }
    }
    if (t == 0) offs[NN] = sums[1023];
    if (t < 10) hcnt[t] = 0;
    __syncthreads();
    for (int n = t; n < NN; n += 1024) {
        int s = specie[n];
        s = ((unsigned)s < 10) ? s : 0;
        atomicAdd(&hcnt[s], 1);
    }
    __syncthreads();
    if (t == 0) {
        int run = 0, tc = 0;
        for (int sp = 0; sp < 10; sp++) {
            hbase[sp] = run; hcur[sp] = run; run += hcnt[sp];
            tbase[sp] = tc;  tc += (hcnt[sp] + 15) >> 4;
        }
        tbase[10] = tc;
        *ntiles = tc;
    }
    __syncthreads();
    const int tc = tbase[10];
    for (int ti = t; ti < tc; ti += 1024) {
        int sp = 0;
        while (sp < 9 && ti >= tbase[sp + 1]) sp++;
        const int b = (ti - tbase[sp]) * 16;
        tiles[ti] = make_int2(hbase[sp] + b, (sp << 8) | min(16, hcnt[sp] - b));
    }
    for (int n = t; n < NN; n += 1024) {
        int s = specie[n];
        s = ((unsigned)s < 10) ? s : 0;
        int slot = atomicAdd(&hcur[s], 1);
        if ((unsigned)slot < NN) perm[slot] = n;
    }
}

// ---------------- pre: h = [s,v]@W_up via MFMA -> h4 interleaved ----------
__global__ __launch_bounds__(256) void k_pre_mfma(
    const float* __restrict__ nf,
    const unsigned short* __restrict__ Tw,
    uint2* __restrict__ h4) {
    const int tile = blockIdx.x;  // 625 tiles of 16 nodes
    const int tid = threadIdx.x;
    const int lane = tid & 63, wv = tid >> 6;
    const int col = lane & 15, quad = lane >> 4;
    __shared__ float nfl[16][512];  // 32 KB
    {
        const float4* src = (const float4*)(nf + (size_t)tile * 16 * 512);
        float4* dst = (float4*)nfl;
        for (int i = tid; i < 2048; i += 256) dst[i] = src[i];
    }
    __syncthreads();
    const float* rp = nfl[col];
    s16x8 Af[4][4];
#pragma unroll
    for (int kt = 0; kt < 4; kt++) {
        const int ko = kt * 32 + quad * 8;
        const float4 fa = *(const float4*)(rp + ko);
        const float4 fb = *(const float4*)(rp + ko + 4);
        Af[0][kt] = pack8(fa, fb);
#pragma unroll
        for (int i = 0; i < 3; i++) {
            union { s16x8 v; unsigned short u[8]; } A;
#pragma unroll
            for (int j = 0; j < 8; j++) A.u[j] = f2bu(rp[128 + 3 * (ko + j) + i]);
            Af[1 + i][kt] = A.v;
        }
    }
    const unsigned short* Ts = Tw;
    const unsigned short* Tv = Tw + 16384;
#pragma unroll
    for (int nt = 0; nt < 2; nt++) {
        const int d = 32 * wv + 16 * nt + col;
        f32x4 C[4];
#pragma unroll
        for (int m = 0; m < 4; m++) C[m] = (f32x4){0.f, 0.f, 0.f, 0.f};
#pragma unroll
        for (int kt = 0; kt < 4; kt++) {
            const int ko = kt * 32 + quad * 8;
            const s16x8 Bs = *(const s16x8*)&Ts[(size_t)d * 128 + ko];
            const s16x8 Bv = *(const s16x8*)&Tv[(size_t)d * 128 + ko];
            C[0] = __builtin_amdgcn_mfma_f32_16x16x32_bf16(Af[0][kt], Bs, C[0], 0, 0, 0);
#pragma unroll
            for (int i = 0; i < 3; i++)
                C[1 + i] = __builtin_amdgcn_mfma_f32_16x16x32_bf16(Af[1 + i][kt], Bv, C[1 + i], 0, 0, 0);
        }
#pragma unroll
        for (int reg = 0; reg < 4; reg++) {
            const int node = tile * 16 + quad * 4 + reg;
            h4[(size_t)node * 128 + d] =
                make_uint2(pack2(C[0][reg], C[1][reg]), pack2(C[2][reg], C[3][reg]));
        }
    }
}

// ------- MFMA edge kernel: 256 thr, 2 tile-groups/wave, lean registers ------
#define EGRID 2560
__global__ __launch_bounds__(256, 2) void k_edge_mfma(
    const float* __restrict__ vectors,
    const float* __restrict__ radial,
    const int* __restrict__ senders,
    const float* __restrict__ W_rad1,
    const unsigned short* __restrict__ w2t,   // [640][64] bf16
    const uint2* __restrict__ h4,             // [N][128] {s,v0,v1,v2} bf16
    const int* __restrict__ offs, const int* __restrict__ csr,
    unsigned short* __restrict__ aggb) {      // [N][4][128] bf16 planar
    __shared__ unsigned short w1s[512];
    __shared__ float4 em[64];
    __shared__ float radl[64][8];
    __shared__ unsigned short hid[64 * 72];
    const int tid = threadIdx.x;
    const int lane = tid & 63, wv = tid >> 6;
    const int row = lane & 15, quad = lane >> 4;
    for (int i = tid; i < 512; i += 256) w1s[i] = f2bu(W_rad1[i]);

    s16x8 Bf[2][5][2];
#pragma unroll
    for (int ti = 0; ti < 2; ti++) {
        const int t = 2 * wv + ti;
#pragma unroll
        for (int p = 0; p < 5; p++) {
            const unsigned short* bp =
                w2t + (size_t)(128 * p + 16 * t + row) * 64 + quad * 8;
            Bf[ti][p][0] = *(const s16x8*)(bp);
            Bf[ti][p][1] = *(const s16x8*)(bp + 32);
        }
    }

    for (int n = blockIdx.x; n < NN; n += EGRID) {
        const int start = offs[n];
        const int deg = offs[n + 1] - start;
        float acc_s[2] = {0.f, 0.f}, av0[2] = {0.f, 0.f},
              av1[2] = {0.f, 0.f}, av2[2] = {0.f, 0.f};

        for (int c0 = 0; c0 < deg; c0 += 64) {
            __syncthreads();
            if (tid < 64) {
                const int i = tid, gi = c0 + i;
                if (gi < deg) {
                    int e = csr[start + gi];
                    e = ((unsigned)e < EE) ? e : 0;
                    int j = senders[e];
                    j = ((unsigned)j < NN) ? j : 0;
                    const float vx = vectors[e * 3 + 0];
                    const float vy = vectors[e * 3 + 1];
                    const float vz = vectors[e * 3 + 2];
                    const float inr = 1.7320508075688772f /
                        (sqrtf(vx * vx + vy * vy + vz * vz) + 1e-9f);
                    em[i] = make_float4(__int_as_float(j), vx * inr, vy * inr, vz * inr);
                    *(float4*)&radl[i][0] = *(const float4*)(radial + (size_t)e * 8);
                    *(float4*)&radl[i][4] = *(const float4*)(radial + (size_t)e * 8 + 4);
                } else {
                    em[i] = make_float4(0.f, 0.f, 0.f, 0.f);
                    *(float4*)&radl[i][0] = make_float4(0.f, 0.f, 0.f, 0.f);
                    *(float4*)&radl[i][4] = make_float4(0.f, 0.f, 0.f, 0.f);
                }
            }
            __syncthreads();
            {   // cooperative hid: thread computes 16 units of one edge
                const int eL = tid >> 2, u0 = (tid & 3) * 16;
                float rr[8];
#pragma unroll
                for (int r = 0; r < 8; r++) rr[r] = radl[eL][r];
                float a[16];
#pragma unroll
                for (int u = 0; u < 16; u++) a[u] = 0.f;
#pragma unroll
                for (int r = 0; r < 8; r++) {
                    const uint4 wa = *(const uint4*)&w1s[r * 64 + u0];
                    const uint4 wb = *(const uint4*)&w1s[r * 64 + u0 + 8];
                    const float f = rr[r];
                    a[0] += f * bflo(wa.x);  a[1] += f * bfhi(wa.x);
                    a[2] += f * bflo(wa.y);  a[3] += f * bfhi(wa.y);
                    a[4] += f * bflo(wa.z);  a[5] += f * bfhi(wa.z);
                    a[6] += f * bflo(wa.w);  a[7] += f * bfhi(wa.w);
                    a[8] += f * bflo(wb.x);  a[9] += f * bfhi(wb.x);
                    a[10] += f * bflo(wb.y); a[11] += f * bfhi(wb.y);
                    a[12] += f * bflo(wb.z); a[13] += f * bfhi(wb.z);
                    a[14] += f * bflo(wb.w); a[15] += f * bfhi(wb.w);
                }
                unsigned o[8];
#pragma unroll
                for (int k = 0; k < 8; k++) {
                    const float s0 = a[2 * k] / (1.f + __expf(-a[2 * k]));
                    const float s1 = a[2 * k + 1] / (1.f + __expf(-a[2 * k + 1]));
                    o[k] = pack2(s0, s1);
                }
                *(uint4*)&hid[eL * 72 + u0] = make_uint4(o[0], o[1], o[2], o[3]);
                *(uint4*)&hid[eL * 72 + u0 + 8] = make_uint4(o[4], o[5], o[6], o[7]);
            }
            __syncthreads();
            const int glim = min(64, deg - c0);
            for (int g0 = 0; g0 < glim; g0 += 16) {
                const s16x8 A0 = *(const s16x8*)&hid[(g0 + row) * 72 + quad * 8];
                const s16x8 A1 = *(const s16x8*)&hid[(g0 + row) * 72 + 32 + quad * 8];
                int jr[4]; float yr0[4], yr1[4], yr2[4];
#pragma unroll
                for (int rg = 0; rg < 4; rg++) {
                    const float4 m = em[g0 + quad * 4 + rg];
                    jr[rg] = __float_as_int(m.x);
                    yr0[rg] = m.y; yr1[rg] = m.z; yr2[rg] = m.w;
                }
#pragma unroll
                for (int ti = 0; ti < 2; ti++) {
                    const int c = 16 * (2 * wv + ti) + row;
                    float sj[4], a0r[4], a1r[4], a2r[4];
#pragma unroll
                    for (int rg = 0; rg < 4; rg++) {
                        const uint2 hh = h4[(size_t)jr[rg] * 128 + c];
                        sj[rg] = bflo(hh.x); a0r[rg] = bfhi(hh.x);
                        a1r[rg] = bflo(hh.y); a2r[rg] = bfhi(hh.y);
                    }
#pragma unroll
                    for (int p = 0; p < 5; p++) {
                        f32x4 z = {0.f, 0.f, 0.f, 0.f};
                        z = __builtin_amdgcn_mfma_f32_16x16x32_bf16(A0, Bf[ti][p][0], z, 0, 0, 0);
                        z = __builtin_amdgcn_mfma_f32_16x16x32_bf16(A1, Bf[ti][p][1], z, 0, 0, 0);
#pragma unroll
                        for (int rg = 0; rg < 4; rg++) {
                            const float w = z[rg];
                            if (p == 0) {
                                acc_s[ti] += w * sj[rg];
                            } else if (p == 1) {
                                const float ws = w * sj[rg];
                                av0[ti] += ws * yr0[rg];
                                av1[ti] += ws * yr1[rg];
                                av2[ti] += ws * yr2[rg];
                            } else if (p == 2) {
                                av0[ti] += w * a0r[rg];
                                av1[ti] += w * a1r[rg];
                                av2[ti] += w * a2r[rg];
                            } else if (p == 3) {
                                acc_s[ti] += w * (a0r[rg] * yr0[rg] + a1r[rg] * yr1[rg] +
                                                  a2r[rg] * yr2[rg]);
                            } else {
                                av0[ti] += w * (a1r[rg] * yr2[rg] - a2r[rg] * yr1[rg]);
                                av1[ti] += w * (a2r[rg] * yr0[rg] - a0r[rg] * yr2[rg]);
                                av2[ti] += w * (a0r[rg] * yr1[rg] - a1r[rg] * yr0[rg]);
                            }
                        }
                    }
                }
            }
        }
#pragma unroll
        for (int ti = 0; ti < 2; ti++) {
            acc_s[ti] += __shfl_xor(acc_s[ti], 16); acc_s[ti] += __shfl_xor(acc_s[ti], 32);
            av0[ti] += __shfl_xor(av0[ti], 16);     av0[ti] += __shfl_xor(av0[ti], 32);
            av1[ti] += __shfl_xor(av1[ti], 16);     av1[ti] += __shfl_xor(av1[ti], 32);
            av2[ti] += __shfl_xor(av2[ti], 16);     av2[ti] += __shfl_xor(av2[ti], 32);
        }
        if (lane < 16) {
            unsigned short* og = aggb + (size_t)n * 512;
#pragma unroll
            for (int ti = 0; ti < 2; ti++) {
                const int cc = 16 * (2 * wv + ti) + lane;
                og[cc] = f2bu(acc_s[ti]);
                og[128 + cc] = f2bu(av0[ti]);
                og[256 + cc] = f2bu(av1[ti]);
                og[384 + cc] = f2bu(av2[ti]);
            }
        }
    }
}

// -------- post: down+skip GEMM -> prod -> P via LDS -> lin GEMM + out ------
__global__ __launch_bounds__(256) void k_post_mfma(
    const float* __restrict__ nf,
    const unsigned short* __restrict__ aggb,
    const int* __restrict__ perm,
    const int2* __restrict__ tiles,
    const int* __restrict__ ntiles,
    const unsigned short* __restrict__ Tw,
    const float* __restrict__ Wps,
    const float* __restrict__ Wpv,
    const float* __restrict__ Wro,
    float* __restrict__ dout) {
    const int tile = blockIdx.x;
    if (tile >= *ntiles) return;
    const int2 td = tiles[tile];
    const int base = td.x, sp = td.y >> 8, cnt = td.y & 255;
    __shared__ int nodesl[16];
    __shared__ float rol[16];
    __shared__ unsigned short Pl[4][16][128];  // 16 KB
    __shared__ float nfl[16][512];             // 32 KB
    const int tid = threadIdx.x;
    if (tid < 16) {
        nodesl[tid] = perm[base + ((tid < cnt) ? tid : 0)];
        rol[tid] = 0.f;
    }
    __syncthreads();
    {
        float4* dst = (float4*)nfl;
        for (int i = tid; i < 2048; i += 256) {
            const int r = i >> 7, off = i & 127;
            dst[i] = ((const float4*)(nf + (size_t)nodesl[r] * 512))[off];
        }
    }
    __syncthreads();
    const int lane = tid & 63, wv = tid >> 6;
    const int col = lane & 15, quad = lane >> 4;
    const int aN = nodesl[col];
    const unsigned short* Tds = Tw + (size_t)2 * 16384;
    const unsigned short* Tdv = Tw + (size_t)3 * 16384;
    const unsigned short* Tls = Tw + (size_t)4 * 16384;
    const unsigned short* Tlv = Tw + (size_t)5 * 16384;
    const unsigned short* Tss = Tw + (size_t)(6 + sp) * 16384;
    const unsigned short* Tsv = Tw + (size_t)(16 + sp) * 16384;
    const float* rp = nfl[col];
    f32x4 SC[2][4];
#pragma unroll
    for (int nt = 0; nt < 2; nt++) {
        const int d = 32 * wv + 16 * nt + col;
        f32x4 CF[4];
#pragma unroll
        for (int m = 0; m < 4; m++) CF[m] = (f32x4){0.f, 0.f, 0.f, 0.f};
#pragma unroll
        for (int kt = 0; kt < 4; kt++) {
            const int ko = kt * 32 + quad * 8;
            const s16x8 Bs = *(const s16x8*)&Tds[(size_t)d * 128 + ko];
            const s16x8 Bv = *(const s16x8*)&Tdv[(size_t)d * 128 + ko];
#pragma unroll
            for (int m = 0; m < 4; m++) {
                const s16x8 A = *(const s16x8*)&aggb[(size_t)aN * 512 + m * 128 + ko];
                CF[m] = __builtin_amdgcn_mfma_f32_16x16x32_bf16(A, m ? Bv : Bs, CF[m], 0, 0, 0);
            }
        }
        const float wps0 = Wps[sp * 384 + d];
        const float wps1 = Wps[sp * 384 + 128 + d];
        const float wps2 = Wps[sp * 384 + 256 + d];
        const float wpv0 = Wpv[sp * 256 + d];
        const float wpv1 = Wpv[sp * 256 + 128 + d];
#pragma unroll
        for (int reg = 0; reg < 4; reg++) {
            const float fs = CF[0][reg] * FEPS;
            const float f0 = CF[1][reg] * FEPS;
            const float f1 = CF[2][reg] * FEPS;
            const float f2 = CF[3][reg] * FEPS;
            const float ps = fs * wps0 + fs * fs * wps1 + (f0 * f0 + f1 * f1 + f2 * f2) * wps2;
            const float pb = wpv0 + fs * wpv1;
            const int r = quad * 4 + reg;
            Pl[0][r][d] = f2bu(ps);
            Pl[1][r][d] = f2bu(f0 * pb);
            Pl[2][r][d] = f2bu(f1 * pb);
            Pl[3][r][d] = f2bu(f2 * pb);
        }
        f32x4 CS[4];
#pragma unroll
        for (int m = 0; m < 4; m++) CS[m] = (f32x4){0.f, 0.f, 0.f, 0.f};
#pragma unroll
        for (int kt = 0; kt < 4; kt++) {
            const int ko = kt * 32 + quad * 8;
            const s16x8 Bss = *(const s16x8*)&Tss[(size_t)d * 128 + ko];
            const s16x8 Bsv = *(const s16x8*)&Tsv[(size_t)d * 128 + ko];
            const float4 fa = *(const float4*)(rp + ko);
            const float4 fb = *(const float4*)(rp + ko + 4);
            CS[0] = __builtin_amdgcn_mfma_f32_16x16x32_bf16(pack8(fa, fb), Bss, CS[0], 0, 0, 0);
#pragma unroll
            for (int i = 0; i < 3; i++) {
                union { s16x8 v; unsigned short u[8]; } A;
#pragma unroll
                for (int j = 0; j < 8; j++) A.u[j] = f2bu(rp[128 + 3 * (ko + j) + i]);
                CS[1 + i] = __builtin_amdgcn_mfma_f32_16x16x32_bf16(A.v, Bsv, CS[1 + i], 0, 0, 0);
            }
        }
#pragma unroll
        for (int m = 0; m < 4; m++) SC[nt][m] = CS[m];
    }
    __syncthreads();
#pragma unroll
    for (int nt = 0; nt < 2; nt++) {
        const int d = 32 * wv + 16 * nt + col;
        f32x4 CL[4];
#pragma unroll
        for (int m = 0; m < 4; m++) CL[m] = (f32x4){0.f, 0.f, 0.f, 0.f};
#pragma unroll
        for (int kt = 0; kt < 4; kt++) {
            const int ko = kt * 32 + quad * 8;
            const s16x8 Bls = *(const s16x8*)&Tls[(size_t)d * 128 + ko];
            const s16x8 Blv = *(const s16x8*)&Tlv[(size_t)d * 128 + ko];
#pragma unroll
            for (int m = 0; m < 4; m++) {
                const s16x8 A = *(const s16x8*)&Pl[m][col][ko];
                CL[m] = __builtin_amdgcn_mfma_f32_16x16x32_bf16(A, m ? Blv : Bls, CL[m], 0, 0, 0);
            }
        }
        const float wro = Wro[d];
#pragma unroll
        for (int reg = 0; reg < 4; reg++) {
            const int r = quad * 4 + reg;
            if (r < cnt) {
                const int node = nodesl[r];
                const float outs = CL[0][reg] + SC[nt][0][reg];
                const float o0 = CL[1][reg] + SC[nt][1][reg];
                const float o1 = CL[2][reg] + SC[nt][2][reg];
                const float o2 = CL[3][reg] + SC[nt][3][reg];
                float* o = dout + NN + (size_t)node * 512;
                o[d] = outs;
                o[128 + 3 * d + 0] = o0;
                o[128 + 3 * d + 1] = o1;
                o[128 + 3 * d + 2] = o2;
                atomicAdd(&rol[r], outs * wro);
            }
        }
    }
    __syncthreads();
    if (tid < 16 && tid < cnt) dout[nodesl[tid]] = rol[tid];
}

extern "C" void kernel_launch(void* const* d_in, const int* in_sizes, int n_in,
                              void* d_out, int out_size, void* d_ws, size_t ws_size,
                              hipStream_t stream) {
    const float* vectors    = (const float*)d_in[0];
    const float* node_feats = (const float*)d_in[1];
    const int*   specie     = (const int*)d_in[2];
    const float* radial     = (const float*)d_in[3];
    const int*   senders    = (const int*)d_in[4];
    const int*   receivers  = (const int*)d_in[5];
    const float* W_up_s     = (const float*)d_in[6];
    const float* W_up_v     = (const float*)d_in[7];
    const float* W_rad1     = (const float*)d_in[8];
    const float* W_rad2     = (const float*)d_in[9];
    const float* W_down_s   = (const float*)d_in[10];
    const float* W_down_v   = (const float*)d_in[11];
    const float* W_skip_s   = (const float*)d_in[12];
    const float* W_skip_v   = (const float*)d_in[13];
    const float* W_prod_s   = (const float*)d_in[14];
    const float* W_prod_v   = (const float*)d_in[15];
    const float* W_lin_s    = (const float*)d_in[16];
    const float* W_lin_v    = (const float*)d_in[17];
    const float* W_ro       = (const float*)d_in[18];
    float* out = (float*)d_out;

    // workspace carve (~23 MB)
    char* w = (char*)d_ws;
    auto align256 = [](size_t x) { return (x + 255) & ~(size_t)255; };
    int* cnt  = (int*)w;              w += align256((size_t)NN * 4);
    int* offs = (int*)w;              w += align256((size_t)(NN + 1) * 4);
    int* cur  = (int*)w;              w += align256((size_t)NN * 4);
    int* csr  = (int*)w;              w += align256((size_t)EE * 4);
    uint2* h4 = (uint2*)w;            w += align256((size_t)NN * 128 * 8);
    unsigned short* aggb = (unsigned short*)w;  w += align256((size_t)NN * 512 * 2);
    unsigned short* w2t  = (unsigned short*)w;  w += align256((size_t)W2N * 2);
    unsigned short* Tw   = (unsigned short*)w;  w += align256((size_t)TWN * 2);
    int* perm   = (int*)w;            w += align256((size_t)NN * 4);
    int2* tiles = (int2*)w;           w += align256((size_t)640 * 8);
    int* ntiles = (int*)w;            w += align256(4);

    k_prep<<<26 + PREPX, 256, 0, stream>>>(
        W_up_s, W_up_v, W_down_s, W_down_v, W_lin_s, W_lin_v,
        W_skip_s, W_skip_v, W_rad2, Tw, w2t, cnt);
    k_hist<<<(EE + 255) / 256, 256, 0, stream>>>(receivers, cnt);
    k_scan_spec<<<1, 1024, 0, stream>>>(cnt, offs, cur, specie, perm, tiles, ntiles);
    k_fill<<<(EE + 255) / 256, 256, 0, stream>>>(receivers, cur, csr);
    k_pre_mfma<<<NN / 16, 256, 0, stream>>>(node_feats, Tw, h4);
    k_edge_mfma<<<EGRID, 256, 0, stream>>>(vectors, radial, senders, W_rad1,
                                           w2t, h4, offs, csr, aggb);
    k_post_mfma<<<640, 256, 0, stream>>>(node_feats, aggb, perm, tiles, ntiles,
                                         Tw, W_prod_s, W_prod_v, W_ro, out);
}